// Round 2
// baseline (763.762 us; speedup 1.0000x reference)
//
#include <hip/hip_runtime.h>
#include <math.h>

// DiT block, fp32 correctness-first implementation.
// b=64, n=512 (8x8x8), d=128, H=4, dk=32.
// Workspace layout (floats): Q[64*512*128] | K | V | O | mods[64*6*128]
// mods slots per b: 0=alpha1(g1), 1=gamma1(be1), 2=beta1(al1),
//                   3=alpha2(g2), 4=gamma2(be2), 5=beta2(al2)   (bug-faithful)

#define NB 64

__device__ __forceinline__ float silu_f(float x) { return x / (1.0f + __expf(-x)); }

// ---------------- K1: cond MLPs ----------------
// grid = NB*4 blocks, 128 threads. block -> (b, mlp)
__global__ void __launch_bounds__(128) k_cond(
    const float* __restrict__ nodes, const float* __restrict__ tv,
    const float* __restrict__ w10, const float* __restrict__ b10,
    const float* __restrict__ w20, const float* __restrict__ b20,
    const float* __restrict__ w30, const float* __restrict__ b30,
    const float* __restrict__ w11, const float* __restrict__ b11,
    const float* __restrict__ w21, const float* __restrict__ b21,
    const float* __restrict__ w31, const float* __restrict__ b31,
    const float* __restrict__ w12, const float* __restrict__ b12,
    const float* __restrict__ w22, const float* __restrict__ b22,
    const float* __restrict__ w32, const float* __restrict__ b32,
    const float* __restrict__ w13, const float* __restrict__ b13,
    const float* __restrict__ w23, const float* __restrict__ b23,
    const float* __restrict__ w33, const float* __restrict__ b33,
    float* __restrict__ mods)
{
    int blk = blockIdx.x;
    int b = blk >> 2, m = blk & 3;
    const float* W1 = m==0?w10 : m==1?w11 : m==2?w12 : w13;
    const float* B1 = m==0?b10 : m==1?b11 : m==2?b12 : b13;
    const float* W2 = m==0?w20 : m==1?w21 : m==2?w22 : w23;
    const float* B2 = m==0?b20 : m==1?b21 : m==2?b22 : b23;
    const float* W3 = m==0?w30 : m==1?w31 : m==2?w32 : w33;
    const float* B3 = m==0?b30 : m==1?b31 : m==2?b32 : b33;
    // an_gb -> slots 0,1 ; an_a -> slot 2 ; fn_gb -> slots 3,4 ; fn_a -> slot 5
    int dout256 = (m == 0 || m == 2);
    int slot = (m==0)?0 : (m==1)?2 : (m==2)?3 : 5;

    __shared__ float xs[128], h1[128], h2[128];
    int t = threadIdx.x;
    xs[t] = nodes[b*128 + t] + tv[b];
    __syncthreads();

    float acc = B1[t];
    for (int i = 0; i < 128; i++) acc += xs[i] * W1[i*128 + t];
    h1[t] = silu_f(acc);
    __syncthreads();

    acc = B2[t];
    for (int i = 0; i < 128; i++) acc += h1[i] * W2[i*128 + t];
    h2[t] = silu_f(acc);
    __syncthreads();

    if (dout256) {
        float a0 = B3[t], a1 = B3[t + 128];
        for (int i = 0; i < 128; i++) {
            float h = h2[i];
            a0 += h * W3[i*256 + t];
            a1 += h * W3[i*256 + t + 128];
        }
        mods[((size_t)b*6 + slot    )*128 + t] = a0;
        mods[((size_t)b*6 + slot + 1)*128 + t] = a1;
    } else {
        float a0 = B3[t];
        for (int i = 0; i < 128; i++) a0 += h2[i] * W3[i*128 + t];
        mods[((size_t)b*6 + slot)*128 + t] = a0;
    }
}

// ---------------- K2: staticLN(ddof=1) + modulate + QKV ----------------
// grid = NB*8 blocks (b, 64-row tile), 256 threads
__global__ void __launch_bounds__(256) k_norm_qkv(
    const float* __restrict__ latent, const float* __restrict__ mods,
    const float* __restrict__ qw, const float* __restrict__ kw, const float* __restrict__ vw,
    const float* __restrict__ qb, const float* __restrict__ kb, const float* __restrict__ vb,
    float* __restrict__ Qo, float* __restrict__ Ko, float* __restrict__ Vo)
{
    __shared__ float xs[64 * 132];   // padded to 132 for 16B-aligned float4 reads
    __shared__ float g1s[128], be1s[128];
    __shared__ float mean_s[64], rstd_s[64];

    int blk = blockIdx.x;
    int b = blk >> 3, n0 = (blk & 7) * 64;
    int t = threadIdx.x;

    if (t < 128) {
        g1s[t]  = mods[((size_t)b*6 + 1)*128 + t];  // gamma1 = be1 (bug)
        be1s[t] = mods[((size_t)b*6 + 2)*128 + t];  // beta1  = al1 (bug)
    }
    const float* lp = latent + (size_t)b*128*512 + n0;
    for (int idx = t; idx < 8192; idx += 256) {
        int d = idx >> 6, j = idx & 63;
        xs[j*132 + d] = lp[(size_t)d*512 + j];
    }
    __syncthreads();

    if (t < 64) {
        float s = 0.f, ss = 0.f;
        for (int i = 0; i < 128; i++) { float v = xs[t*132 + i]; s += v; ss += v*v; }
        float mean = s * (1.0f/128.0f);
        float var = (ss - 128.0f*mean*mean) * (1.0f/127.0f);
        var = var < 0.f ? 0.f : var;
        float sd = sqrtf(var);
        mean_s[t] = mean;
        rstd_s[t] = (sd == 0.f) ? 1.f : 1.f/sd;
    }
    __syncthreads();

    for (int idx = t; idx < 8192; idx += 256) {
        int j = idx >> 7, d = idx & 127;
        float v = xs[j*132 + d];
        xs[j*132 + d] = g1s[d]*((v - mean_s[j]) * rstd_s[j]) + be1s[d];
    }
    __syncthreads();

    // QKV: thread -> col c (=h*32+k), 32 rows j = 2r + (t>>7)
    int c = t & 127, jb = t >> 7;
    int h = c >> 5, k = c & 31;
    const float* wq = qw + h*4096 + k;
    const float* wk = kw + h*4096 + k;
    const float* wv = vw + h*4096 + k;

    float aq[32], ak[32], av[32];
    float bq = qb[c], bk2 = kb[c], bv = vb[c];
    #pragma unroll
    for (int r = 0; r < 32; r++) { aq[r] = bq; ak[r] = bk2; av[r] = bv; }

    for (int d0 = 0; d0 < 128; d0 += 4) {
        float wqv[4], wkv[4], wvv[4];
        #pragma unroll
        for (int e = 0; e < 4; e++) {
            wqv[e] = wq[(d0 + e)*32];
            wkv[e] = wk[(d0 + e)*32];
            wvv[e] = wv[(d0 + e)*32];
        }
        #pragma unroll
        for (int r = 0; r < 32; r++) {
            const float4 xv = *reinterpret_cast<const float4*>(&xs[(2*r + jb)*132 + d0]);
            aq[r] += xv.x*wqv[0] + xv.y*wqv[1] + xv.z*wqv[2] + xv.w*wqv[3];
            ak[r] += xv.x*wkv[0] + xv.y*wkv[1] + xv.z*wkv[2] + xv.w*wkv[3];
            av[r] += xv.x*wvv[0] + xv.y*wvv[1] + xv.z*wvv[2] + xv.w*wvv[3];
        }
    }

    float* qrow = Qo + ((size_t)(b*512 + n0))*128 + c;
    float* krow = Ko + ((size_t)(b*512 + n0))*128 + c;
    float* vrow = Vo + ((size_t)(b*512 + n0))*128 + c;
    #pragma unroll
    for (int r = 0; r < 32; r++) {
        int j = 2*r + jb;
        qrow[(size_t)j*128] = aq[r];
        krow[(size_t)j*128] = ak[r];
        vrow[(size_t)j*128] = av[r];
    }
}

// ---------------- K3: attention per (b,h) ----------------
// grid = NB*4 blocks, 256 threads. K LDS-resident (64 KiB); V streamed from
// global (L2-resident). 2 rows/thread.
__global__ void __launch_bounds__(256, 2) k_attn(
    const float* __restrict__ Qg, const float* __restrict__ Kg,
    const float* __restrict__ Vg, float* __restrict__ Og)
{
    __shared__ float Ks[512 * 32];
    int blk = blockIdx.x;
    int b = blk >> 2, h = blk & 3;
    int t = threadIdx.x;

    const float* kp = Kg + (size_t)b*512*128 + h*32;
    const float* vbase = Vg + (size_t)b*512*128 + h*32;
    for (int idx = t; idx < 512*32; idx += 256) {
        int m = idx >> 5, k = idx & 31;
        Ks[idx] = kp[(size_t)m*128 + k];
    }
    __syncthreads();

    const float scale = 0.17677669529663687f; // 1/sqrt(32)
    float q0[32], q1[32];
    const float* q0p = Qg + ((size_t)(b*512 + t))*128 + h*32;
    const float* q1p = q0p + (size_t)256*128;
    #pragma unroll
    for (int k = 0; k < 32; k += 4) {
        float4 a = *reinterpret_cast<const float4*>(q0p + k);
        float4 c = *reinterpret_cast<const float4*>(q1p + k);
        q0[k] = a.x; q0[k+1] = a.y; q0[k+2] = a.z; q0[k+3] = a.w;
        q1[k] = c.x; q1[k+1] = c.y; q1[k+2] = c.z; q1[k+3] = c.w;
    }
    float o0[32], o1[32];
    #pragma unroll
    for (int k = 0; k < 32; k++) { o0[k] = 0.f; o1[k] = 0.f; }
    float mx0 = -1e30f, mx1 = -1e30f, sm0 = 0.f, sm1 = 0.f;

    for (int m0 = 0; m0 < 512; m0 += 8) {
        float s0[8], s1[8];
        #pragma unroll
        for (int jj = 0; jj < 8; jj++) { s0[jj] = 0.f; s1[jj] = 0.f; }
        #pragma unroll
        for (int kk = 0; kk < 32; kk += 4) {
            #pragma unroll
            for (int jj = 0; jj < 8; jj++) {
                float4 kv = *reinterpret_cast<const float4*>(&Ks[(m0 + jj)*32 + kk]);
                s0[jj] += q0[kk]*kv.x + q0[kk+1]*kv.y + q0[kk+2]*kv.z + q0[kk+3]*kv.w;
                s1[jj] += q1[kk]*kv.x + q1[kk+1]*kv.y + q1[kk+2]*kv.z + q1[kk+3]*kv.w;
            }
        }
        #pragma unroll
        for (int jj = 0; jj < 8; jj++) { s0[jj] *= scale; s1[jj] *= scale; }

        float cm0 = fmaxf(fmaxf(fmaxf(s0[0],s0[1]),fmaxf(s0[2],s0[3])),
                          fmaxf(fmaxf(s0[4],s0[5]),fmaxf(s0[6],s0[7])));
        float cm1 = fmaxf(fmaxf(fmaxf(s1[0],s1[1]),fmaxf(s1[2],s1[3])),
                          fmaxf(fmaxf(s1[4],s1[5]),fmaxf(s1[6],s1[7])));
        float nm0 = fmaxf(mx0, cm0), nm1 = fmaxf(mx1, cm1);
        float rs0 = __expf(mx0 - nm0), rs1 = __expf(mx1 - nm1);
        sm0 *= rs0; sm1 *= rs1;
        #pragma unroll
        for (int k = 0; k < 32; k++) { o0[k] *= rs0; o1[k] *= rs1; }

        #pragma unroll
        for (int jj = 0; jj < 8; jj++) {
            float p0 = __expf(s0[jj] - nm0);
            float p1 = __expf(s1[jj] - nm1);
            sm0 += p0; sm1 += p1;
            const float* vr = vbase + (size_t)(m0 + jj)*128;
            #pragma unroll
            for (int k = 0; k < 32; k += 4) {
                float4 vv = *reinterpret_cast<const float4*>(vr + k);
                o0[k]   += p0*vv.x; o0[k+1] += p0*vv.y; o0[k+2] += p0*vv.z; o0[k+3] += p0*vv.w;
                o1[k]   += p1*vv.x; o1[k+1] += p1*vv.y; o1[k+2] += p1*vv.z; o1[k+3] += p1*vv.w;
            }
        }
        mx0 = nm0; mx1 = nm1;
    }

    float inv0 = 1.f / sm0, inv1 = 1.f / sm1;
    float* o0p = Og + ((size_t)(b*512 + t))*128 + h*32;
    float* o1p = o0p + (size_t)256*128;
    #pragma unroll
    for (int k = 0; k < 32; k++) { o0p[k] = o0[k]*inv0; o1p[k] = o1[k]*inv1; }
}

// ---------------- K4: O-permute @ ow + residual + staticLN2 + residual + transpose-out ----
// grid = NB*8 blocks, 256 threads
__global__ void __launch_bounds__(256) k_out(
    const float* __restrict__ latent, const float* __restrict__ Og,
    const float* __restrict__ ow, const float* __restrict__ mods,
    float* __restrict__ outp)
{
    __shared__ float os[64 * 132];
    __shared__ float xs[64 * 129];
    __shared__ float a1s[128], a2s[128], g2s[128], b2s[128];
    __shared__ float mean_s[64], rstd_s[64];

    int blk = blockIdx.x;
    int b = blk >> 3, n0 = (blk & 7) * 64;
    int t = threadIdx.x;

    if (t < 128) {
        a1s[t] = mods[((size_t)b*6 + 0)*128 + t];  // alpha1 = g1 (bug)
        a2s[t] = mods[((size_t)b*6 + 3)*128 + t];  // alpha2 = g2 (bug)
        g2s[t] = mods[((size_t)b*6 + 4)*128 + t];  // gamma2 = be2 (bug)
        b2s[t] = mods[((size_t)b*6 + 5)*128 + t];  // beta2  = al2 (bug)
    }
    const float* op = Og + ((size_t)(b*512 + n0))*128;
    for (int idx = t; idx < 8192; idx += 256) {
        int j = idx >> 7, cc = idx & 127;
        os[j*132 + cc] = op[(size_t)j*128 + cc];
    }
    const float* lp = latent + (size_t)b*128*512 + n0;
    for (int idx = t; idx < 8192; idx += 256) {
        int d = idx >> 6, j = idx & 63;
        xs[j*129 + d] = lp[(size_t)d*512 + j];
    }
    __syncthreads();

    // attn = O_perm @ ow; O_flat[i] with i = k*4+h lives at stored col sc = h*32+k,
    // i.e. iterate sc, use ow row i = (sc&31)*4 + (sc>>5).
    int c = t & 127, jb = t >> 7;
    float acc[32];
    #pragma unroll
    for (int r = 0; r < 32; r++) acc[r] = 0.f;

    for (int sc0 = 0; sc0 < 128; sc0 += 4) {
        float w[4];
        #pragma unroll
        for (int e = 0; e < 4; e++) {
            int sc = sc0 + e;
            int i = (sc & 31)*4 + (sc >> 5);
            w[e] = ow[i*128 + c];
        }
        #pragma unroll
        for (int r = 0; r < 32; r++) {
            float4 ov = *reinterpret_cast<const float4*>(&os[(2*r + jb)*132 + sc0]);
            acc[r] += ov.x*w[0] + ov.y*w[1] + ov.z*w[2] + ov.w*w[3];
        }
    }
    #pragma unroll
    for (int r = 0; r < 32; r++) {
        int j = 2*r + jb;
        xs[j*129 + c] += a1s[c] * acc[r];
    }
    __syncthreads();

    if (t < 64) {
        float s = 0.f, ss = 0.f;
        for (int i = 0; i < 128; i++) { float v = xs[t*129 + i]; s += v; ss += v*v; }
        float mean = s * (1.0f/128.0f);
        float var = (ss - 128.0f*mean*mean) * (1.0f/127.0f);
        var = var < 0.f ? 0.f : var;
        float sd = sqrtf(var);
        mean_s[t] = mean;
        rstd_s[t] = (sd == 0.f) ? 1.f : 1.f/sd;
    }
    __syncthreads();

    float* outb = outp + (size_t)b*128*512 + n0;
    for (int idx = t; idx < 8192; idx += 256) {
        int d = idx >> 6, j = idx & 63;
        float v = xs[j*129 + d];
        float nv = (v - mean_s[j]) * rstd_s[j];
        outb[(size_t)d*512 + j] = v + a2s[d]*(g2s[d]*nv + b2s[d]);
    }
}

extern "C" void kernel_launch(void* const* d_in, const int* in_sizes, int n_in,
                              void* d_out, int out_size, void* d_ws, size_t ws_size,
                              hipStream_t stream) {
    const float* latent = (const float*)d_in[0];
    const float* nodes  = (const float*)d_in[1];
    const float* tv     = (const float*)d_in[2];
    const float* qw     = (const float*)d_in[3];
    const float* kw     = (const float*)d_in[4];
    const float* vw     = (const float*)d_in[5];
    const float* qb     = (const float*)d_in[6];
    const float* kb     = (const float*)d_in[7];
    const float* vb     = (const float*)d_in[8];
    const float* owp    = (const float*)d_in[9];

    // 4 MLPs x (w1,b1,w2,b2,w3,b3) starting at index 10:
    // 10..15 an_gb, 16..21 an_a, 22..27 fn_gb, 28..33 fn_a
    const float* mw[24];
    for (int i = 0; i < 24; i++) mw[i] = (const float*)d_in[10 + i];

    float* wsf  = (float*)d_ws;
    float* Q    = wsf;
    float* K    = wsf + 4194304;   // 64*512*128
    float* V    = wsf + 8388608;
    float* O    = wsf + 12582912;
    float* mods = wsf + 16777216;  // 64*6*128 floats

    float* outp = (float*)d_out;

    k_cond<<<dim3(NB*4), dim3(128), 0, stream>>>(
        nodes, tv,
        mw[0], mw[1], mw[2], mw[3], mw[4], mw[5],
        mw[6], mw[7], mw[8], mw[9], mw[10], mw[11],
        mw[12], mw[13], mw[14], mw[15], mw[16], mw[17],
        mw[18], mw[19], mw[20], mw[21], mw[22], mw[23],
        mods);

    k_norm_qkv<<<dim3(NB*8), dim3(256), 0, stream>>>(
        latent, mods, qw, kw, vw, qb, kb, vb, Q, K, V);

    k_attn<<<dim3(NB*4), dim3(256), 0, stream>>>(Q, K, V, O);

    k_out<<<dim3(NB*8), dim3(256), 0, stream>>>(latent, O, owp, mods, outp);
}

// Round 3
// 309.412 us; speedup vs baseline: 2.4684x; 2.4684x over previous
//
#include <hip/hip_runtime.h>
#include <hip/hip_bf16.h>
#include <math.h>

// DiT block. b=64, n=512 (8x8x8), d=128, H=4, dk=32.
// Round 3: MFMA bf16 attention.
// ws layout (bytes):
//   Qb  bf16 [64][4][512][32]   8 MB   (pre-scaled by 1/sqrt(32))
//   Kb  bf16 [64][4][512][32]   8 MB
//   Vtb bf16 [64][4][32][512]   8 MB   (transposed: [d][k])
//   Og  f32  [64][512][128]    16 MB
//   mods f32 [64][6][128]      192 KB
// mods slots per b: 0=alpha1(g1), 1=gamma1(be1), 2=beta1(al1),
//                   3=alpha2(g2), 4=gamma2(be2), 5=beta2(al2)   (bug-faithful)

#define NB 64

typedef __attribute__((ext_vector_type(8))) short bf16x8;
typedef __attribute__((ext_vector_type(4))) float f32x4;

__device__ __forceinline__ float silu_f(float x) { return x / (1.0f + __expf(-x)); }
__device__ __forceinline__ unsigned short f2bf(float x) {
    __hip_bfloat16 h = __float2bfloat16(x);
    return *reinterpret_cast<unsigned short*>(&h);
}

// ---------------- K1: cond MLPs ----------------
// grid = NB*4 blocks, 128 threads. block -> (b, mlp)
__global__ void __launch_bounds__(128) k_cond(
    const float* __restrict__ nodes, const float* __restrict__ tv,
    const float* __restrict__ w10, const float* __restrict__ b10,
    const float* __restrict__ w20, const float* __restrict__ b20,
    const float* __restrict__ w30, const float* __restrict__ b30,
    const float* __restrict__ w11, const float* __restrict__ b11,
    const float* __restrict__ w21, const float* __restrict__ b21,
    const float* __restrict__ w31, const float* __restrict__ b31,
    const float* __restrict__ w12, const float* __restrict__ b12,
    const float* __restrict__ w22, const float* __restrict__ b22,
    const float* __restrict__ w32, const float* __restrict__ b32,
    const float* __restrict__ w13, const float* __restrict__ b13,
    const float* __restrict__ w23, const float* __restrict__ b23,
    const float* __restrict__ w33, const float* __restrict__ b33,
    float* __restrict__ mods)
{
    int blk = blockIdx.x;
    int b = blk >> 2, m = blk & 3;
    const float* W1 = m==0?w10 : m==1?w11 : m==2?w12 : w13;
    const float* B1 = m==0?b10 : m==1?b11 : m==2?b12 : b13;
    const float* W2 = m==0?w20 : m==1?w21 : m==2?w22 : w23;
    const float* B2 = m==0?b20 : m==1?b21 : m==2?b22 : b23;
    const float* W3 = m==0?w30 : m==1?w31 : m==2?w32 : w33;
    const float* B3 = m==0?b30 : m==1?b31 : m==2?b32 : b33;
    int dout256 = (m == 0 || m == 2);
    int slot = (m==0)?0 : (m==1)?2 : (m==2)?3 : 5;

    __shared__ float xs[128], h1[128], h2[128];
    int t = threadIdx.x;
    xs[t] = nodes[b*128 + t] + tv[b];
    __syncthreads();

    float acc = B1[t];
    for (int i = 0; i < 128; i++) acc += xs[i] * W1[i*128 + t];
    h1[t] = silu_f(acc);
    __syncthreads();

    acc = B2[t];
    for (int i = 0; i < 128; i++) acc += h1[i] * W2[i*128 + t];
    h2[t] = silu_f(acc);
    __syncthreads();

    if (dout256) {
        float a0 = B3[t], a1 = B3[t + 128];
        for (int i = 0; i < 128; i++) {
            float h = h2[i];
            a0 += h * W3[i*256 + t];
            a1 += h * W3[i*256 + t + 128];
        }
        mods[((size_t)b*6 + slot    )*128 + t] = a0;
        mods[((size_t)b*6 + slot + 1)*128 + t] = a1;
    } else {
        float a0 = B3[t];
        for (int i = 0; i < 128; i++) a0 += h2[i] * W3[i*128 + t];
        mods[((size_t)b*6 + slot)*128 + t] = a0;
    }
}

// ---------------- K2: staticLN(ddof=1) + modulate + QKV -> bf16 ----------------
// grid = NB*8 blocks (b, 64-row tile), 256 threads
__global__ void __launch_bounds__(256) k_norm_qkv(
    const float* __restrict__ latent, const float* __restrict__ mods,
    const float* __restrict__ qw, const float* __restrict__ kw, const float* __restrict__ vw,
    const float* __restrict__ qb, const float* __restrict__ kb, const float* __restrict__ vb,
    __hip_bfloat16* __restrict__ Qb, __hip_bfloat16* __restrict__ Kb,
    __hip_bfloat16* __restrict__ Vtb)
{
    __shared__ float xs[64 * 132];
    __shared__ float g1s[128], be1s[128];
    __shared__ float mean_s[64], rstd_s[64];

    int blk = blockIdx.x;
    int b = blk >> 3, n0 = (blk & 7) * 64;
    int t = threadIdx.x;

    if (t < 128) {
        g1s[t]  = mods[((size_t)b*6 + 1)*128 + t];  // gamma1 = be1 (bug)
        be1s[t] = mods[((size_t)b*6 + 2)*128 + t];  // beta1  = al1 (bug)
    }
    const float* lp = latent + (size_t)b*128*512 + n0;
    for (int idx = t; idx < 8192; idx += 256) {
        int d = idx >> 6, j = idx & 63;
        xs[j*132 + d] = lp[(size_t)d*512 + j];
    }
    __syncthreads();

    if (t < 64) {
        float s = 0.f, ss = 0.f;
        for (int i = 0; i < 128; i++) { float v = xs[t*132 + i]; s += v; ss += v*v; }
        float mean = s * (1.0f/128.0f);
        float var = (ss - 128.0f*mean*mean) * (1.0f/127.0f);
        var = var < 0.f ? 0.f : var;
        float sd = sqrtf(var);
        mean_s[t] = mean;
        rstd_s[t] = (sd == 0.f) ? 1.f : 1.f/sd;
    }
    __syncthreads();

    for (int idx = t; idx < 8192; idx += 256) {
        int j = idx >> 7, d = idx & 127;
        float v = xs[j*132 + d];
        xs[j*132 + d] = g1s[d]*((v - mean_s[j]) * rstd_s[j]) + be1s[d];
    }
    __syncthreads();

    int c = t & 127, jb = t >> 7;
    int h = c >> 5, k = c & 31;
    const float* wq = qw + h*4096 + k;
    const float* wk = kw + h*4096 + k;
    const float* wv = vw + h*4096 + k;

    float aq[32], ak[32], av[32];
    float bq = qb[c], bk2 = kb[c], bv = vb[c];
    #pragma unroll
    for (int r = 0; r < 32; r++) { aq[r] = bq; ak[r] = bk2; av[r] = bv; }

    for (int d0 = 0; d0 < 128; d0 += 4) {
        float wqv[4], wkv[4], wvv[4];
        #pragma unroll
        for (int e = 0; e < 4; e++) {
            wqv[e] = wq[(d0 + e)*32];
            wkv[e] = wk[(d0 + e)*32];
            wvv[e] = wv[(d0 + e)*32];
        }
        #pragma unroll
        for (int r = 0; r < 32; r++) {
            const float4 xv = *reinterpret_cast<const float4*>(&xs[(2*r + jb)*132 + d0]);
            aq[r] += xv.x*wqv[0] + xv.y*wqv[1] + xv.z*wqv[2] + xv.w*wqv[3];
            ak[r] += xv.x*wkv[0] + xv.y*wkv[1] + xv.z*wkv[2] + xv.w*wkv[3];
            av[r] += xv.x*wvv[0] + xv.y*wvv[1] + xv.z*wvv[2] + xv.w*wvv[3];
        }
    }

    const float qscale = 0.17677669529663687f; // 1/sqrt(32), folded into Q
    size_t bh = (size_t)(b*4 + h);
    __hip_bfloat16* qrow = Qb + (bh*512 + n0)*32 + k;
    __hip_bfloat16* krow = Kb + (bh*512 + n0)*32 + k;
    __hip_bfloat16* vcol = Vtb + (bh*32 + k)*512 + n0;
    #pragma unroll
    for (int r = 0; r < 32; r++) {
        int j = 2*r + jb;
        qrow[(size_t)j*32] = __float2bfloat16(aq[r] * qscale);
        krow[(size_t)j*32] = __float2bfloat16(ak[r]);
        vcol[j]            = __float2bfloat16(av[r]);
    }
}

// ---------------- K3: MFMA attention per (b,h) ----------------
// grid = NB*4 blocks, 256 threads (4 waves). Each wave: 128 q-rows.
// LDS: K[512][32] bf16 (32KB) + Vt[32][512] bf16 swizzled (32KB) + P 4x16KB = 128KB.
__global__ void __launch_bounds__(256, 1) k_attn(
    const __hip_bfloat16* __restrict__ Qb, const __hip_bfloat16* __restrict__ Kb,
    const __hip_bfloat16* __restrict__ Vtb, float* __restrict__ Og)
{
    __shared__ unsigned short KsS[512*32];
    __shared__ unsigned short VsS[32*512];
    __shared__ unsigned short Ps[4][16*512];

    int bh = blockIdx.x;
    int t = threadIdx.x;

    // stage K (linear) and Vt (XOR-swizzled: elem col ^= (row&7)<<3)
    const unsigned short* kgp = (const unsigned short*)Kb + (size_t)bh*512*32;
    const unsigned short* vgp = (const unsigned short*)Vtb + (size_t)bh*32*512;
    for (int idx = t; idx < 2048; idx += 256) {
        *(bf16x8*)(KsS + idx*8) = *(const bf16x8*)(kgp + idx*8);
    }
    for (int idx = t; idx < 2048; idx += 256) {
        int r = idx >> 6, cch = idx & 63;
        *(bf16x8*)(VsS + r*512 + ((cch*8) ^ ((r&7)<<3))) =
            *(const bf16x8*)(vgp + r*512 + cch*8);
    }
    __syncthreads();

    int w = t >> 6, lane = t & 63, lo = lane & 15, hi = lane >> 4;
    unsigned short* Pw = &Ps[w][0];
    const unsigned short* qbase = (const unsigned short*)Qb + (size_t)bh*512*32;

    const f32x4 zero = {0.f, 0.f, 0.f, 0.f};

    for (int qt = 0; qt < 8; ++qt) {
        int q0 = w*128 + qt*16;
        bf16x8 qa = *(const bf16x8*)(qbase + (size_t)(q0 + lo)*32 + hi*8);

        // --- QK^T: S tile rows q0..q0+15, all 512 k-cols ---
        f32x4 s[32];
        #pragma unroll
        for (int kt = 0; kt < 32; ++kt) {
            bf16x8 kf = *(const bf16x8*)(KsS + (kt*16 + lo)*32 + hi*8);
            s[kt] = __builtin_amdgcn_mfma_f32_16x16x32_bf16(qa, kf, zero, 0, 0, 0);
        }

        // --- row softmax (D layout: row = hi*4+j, col = lo) ---
        float mrow[4] = {-1e30f, -1e30f, -1e30f, -1e30f};
        #pragma unroll
        for (int kt = 0; kt < 32; ++kt) {
            #pragma unroll
            for (int j = 0; j < 4; ++j) mrow[j] = fmaxf(mrow[j], s[kt][j]);
        }
        #pragma unroll
        for (int j = 0; j < 4; ++j) {
            #pragma unroll
            for (int off = 1; off < 16; off <<= 1)
                mrow[j] = fmaxf(mrow[j], __shfl_xor(mrow[j], off));
        }

        float ssum[4] = {0.f, 0.f, 0.f, 0.f};
        #pragma unroll
        for (int kt = 0; kt < 32; ++kt) {
            #pragma unroll
            for (int j = 0; j < 4; ++j) {
                float p = __expf(s[kt][j] - mrow[j]);
                ssum[j] += p;
                int row = hi*4 + j;
                Pw[row*512 + ((kt*16 + lo) ^ ((row&7)<<3))] = f2bf(p);
            }
        }
        #pragma unroll
        for (int j = 0; j < 4; ++j) {
            #pragma unroll
            for (int off = 1; off < 16; off <<= 1)
                ssum[j] += __shfl_xor(ssum[j], off);
        }

        // --- PV: O[q][d] = sum_k P[q][k] Vt[d][k] (B^T pattern) ---
        f32x4 oa = zero, ob = zero;
        const unsigned short* Pl = Pw + lo*512;
        const unsigned short* Vl0 = VsS + lo*512;
        const unsigned short* Vl1 = VsS + (16 + lo)*512;
        int swz = (lo & 7) << 3;
        #pragma unroll
        for (int cc = 0; cc < 16; ++cc) {
            int off = (cc*32 + hi*8) ^ swz;
            bf16x8 pa = *(const bf16x8*)(Pl + off);
            bf16x8 v0 = *(const bf16x8*)(Vl0 + off);
            bf16x8 v1 = *(const bf16x8*)(Vl1 + off);
            oa = __builtin_amdgcn_mfma_f32_16x16x32_bf16(pa, v0, oa, 0, 0, 0);
            ob = __builtin_amdgcn_mfma_f32_16x16x32_bf16(pa, v1, ob, 0, 0, 0);
        }

        // --- store O (f32), deferred 1/sum ---
        int b = bh >> 2, h = bh & 3;
        float* op = Og + ((size_t)(b*512 + q0 + hi*4))*128 + h*32 + lo;
        #pragma unroll
        for (int j = 0; j < 4; ++j) {
            float invj = 1.f / ssum[j];
            op[(size_t)j*128]      = oa[j] * invj;
            op[(size_t)j*128 + 16] = ob[j] * invj;
        }
    }
}

// ---------------- K4: O-permute @ ow + residual + staticLN2 + residual + transpose-out ----
// grid = NB*8 blocks, 256 threads
__global__ void __launch_bounds__(256) k_out(
    const float* __restrict__ latent, const float* __restrict__ Og,
    const float* __restrict__ ow, const float* __restrict__ mods,
    float* __restrict__ outp)
{
    __shared__ float os[64 * 132];
    __shared__ float xs[64 * 129];
    __shared__ float a1s[128], a2s[128], g2s[128], b2s[128];
    __shared__ float mean_s[64], rstd_s[64];

    int blk = blockIdx.x;
    int b = blk >> 3, n0 = (blk & 7) * 64;
    int t = threadIdx.x;

    if (t < 128) {
        a1s[t] = mods[((size_t)b*6 + 0)*128 + t];  // alpha1 = g1 (bug)
        a2s[t] = mods[((size_t)b*6 + 3)*128 + t];  // alpha2 = g2 (bug)
        g2s[t] = mods[((size_t)b*6 + 4)*128 + t];  // gamma2 = be2 (bug)
        b2s[t] = mods[((size_t)b*6 + 5)*128 + t];  // beta2  = al2 (bug)
    }
    const float* op = Og + ((size_t)(b*512 + n0))*128;
    for (int idx = t; idx < 8192; idx += 256) {
        int j = idx >> 7, cc = idx & 127;
        os[j*132 + cc] = op[(size_t)j*128 + cc];
    }
    const float* lp = latent + (size_t)b*128*512 + n0;
    for (int idx = t; idx < 8192; idx += 256) {
        int d = idx >> 6, j = idx & 63;
        xs[j*129 + d] = lp[(size_t)d*512 + j];
    }
    __syncthreads();

    // attn = O_perm @ ow; stored col sc = h*32+k -> ow row i = (sc&31)*4 + (sc>>5)
    int c = t & 127, jb = t >> 7;
    float acc[32];
    #pragma unroll
    for (int r = 0; r < 32; r++) acc[r] = 0.f;

    for (int sc0 = 0; sc0 < 128; sc0 += 4) {
        float wv4[4];
        #pragma unroll
        for (int e = 0; e < 4; e++) {
            int sc = sc0 + e;
            int i = (sc & 31)*4 + (sc >> 5);
            wv4[e] = ow[i*128 + c];
        }
        #pragma unroll
        for (int r = 0; r < 32; r++) {
            float4 ov = *reinterpret_cast<const float4*>(&os[(2*r + jb)*132 + sc0]);
            acc[r] += ov.x*wv4[0] + ov.y*wv4[1] + ov.z*wv4[2] + ov.w*wv4[3];
        }
    }
    #pragma unroll
    for (int r = 0; r < 32; r++) {
        int j = 2*r + jb;
        xs[j*129 + c] += a1s[c] * acc[r];
    }
    __syncthreads();

    if (t < 64) {
        float s = 0.f, ss = 0.f;
        for (int i = 0; i < 128; i++) { float v = xs[t*129 + i]; s += v; ss += v*v; }
        float mean = s * (1.0f/128.0f);
        float var = (ss - 128.0f*mean*mean) * (1.0f/127.0f);
        var = var < 0.f ? 0.f : var;
        float sd = sqrtf(var);
        mean_s[t] = mean;
        rstd_s[t] = (sd == 0.f) ? 1.f : 1.f/sd;
    }
    __syncthreads();

    float* outb = outp + (size_t)b*128*512 + n0;
    for (int idx = t; idx < 8192; idx += 256) {
        int d = idx >> 6, j = idx & 63;
        float v = xs[j*129 + d];
        float nv = (v - mean_s[j]) * rstd_s[j];
        outb[(size_t)d*512 + j] = v + a2s[d]*(g2s[d]*nv + b2s[d]);
    }
}

extern "C" void kernel_launch(void* const* d_in, const int* in_sizes, int n_in,
                              void* d_out, int out_size, void* d_ws, size_t ws_size,
                              hipStream_t stream) {
    const float* latent = (const float*)d_in[0];
    const float* nodes  = (const float*)d_in[1];
    const float* tv     = (const float*)d_in[2];
    const float* qw     = (const float*)d_in[3];
    const float* kw     = (const float*)d_in[4];
    const float* vw     = (const float*)d_in[5];
    const float* qb     = (const float*)d_in[6];
    const float* kb     = (const float*)d_in[7];
    const float* vb     = (const float*)d_in[8];
    const float* owp    = (const float*)d_in[9];

    const float* mw[24];
    for (int i = 0; i < 24; i++) mw[i] = (const float*)d_in[10 + i];

    char* wsb = (char*)d_ws;
    __hip_bfloat16* Qb  = (__hip_bfloat16*)(wsb);
    __hip_bfloat16* Kb  = (__hip_bfloat16*)(wsb + 8388608);
    __hip_bfloat16* Vtb = (__hip_bfloat16*)(wsb + 16777216);
    float* Og   = (float*)(wsb + 25165824);
    float* mods = (float*)(wsb + 41943040);

    float* outp = (float*)d_out;

    k_cond<<<dim3(NB*4), dim3(128), 0, stream>>>(
        nodes, tv,
        mw[0], mw[1], mw[2], mw[3], mw[4], mw[5],
        mw[6], mw[7], mw[8], mw[9], mw[10], mw[11],
        mw[12], mw[13], mw[14], mw[15], mw[16], mw[17],
        mw[18], mw[19], mw[20], mw[21], mw[22], mw[23],
        mods);

    k_norm_qkv<<<dim3(NB*8), dim3(256), 0, stream>>>(
        latent, mods, qw, kw, vw, qb, kb, vb, Qb, Kb, Vtb);

    k_attn<<<dim3(NB*4), dim3(256), 0, stream>>>(Qb, Kb, Vtb, Og);

    k_out<<<dim3(NB*8), dim3(256), 0, stream>>>(latent, Og, owp, mods, outp);
}

// Round 4
// 246.524 us; speedup vs baseline: 3.0981x; 1.2551x over previous
//
#include <hip/hip_runtime.h>
#include <hip/hip_bf16.h>
#include <math.h>

// DiT block. b=64, n=512 (8x8x8), d=128, H=4, dk=32.
// Round 4: MFMA everywhere (QKV-proj, attention, O-proj).
// ws layout (bytes):
//   Qb  bf16 [64][4][512][32]   8 MB  (pre-scaled by 1/sqrt(32))
//   Kb  bf16 [64][4][512][32]   8 MB
//   Vtb bf16 [64][4][32][512]   8 MB  (transposed [dk][n])
//   Ob  bf16 [64][512][128]     8 MB  (i-ordered: i = k*4+h, permute pre-applied)
//   mods f32 [64][6][128]      192 KB
// mods slots per b: 0=alpha1(g1), 1=gamma1(be1), 2=beta1(al1),
//                   3=alpha2(g2), 4=gamma2(be2), 5=beta2(al2)   (bug-faithful)

#define NB 64

typedef __attribute__((ext_vector_type(8))) short bf16x8;
typedef __attribute__((ext_vector_type(4))) float f32x4;

__device__ __forceinline__ float silu_f(float x) { return x / (1.0f + __expf(-x)); }
__device__ __forceinline__ unsigned short f2bf(float x) {
    __hip_bfloat16 h = __float2bfloat16(x);
    return *reinterpret_cast<unsigned short*>(&h);
}

// ---------------- K1: cond MLPs ----------------
__global__ void __launch_bounds__(128) k_cond(
    const float* __restrict__ nodes, const float* __restrict__ tv,
    const float* __restrict__ w10, const float* __restrict__ b10,
    const float* __restrict__ w20, const float* __restrict__ b20,
    const float* __restrict__ w30, const float* __restrict__ b30,
    const float* __restrict__ w11, const float* __restrict__ b11,
    const float* __restrict__ w21, const float* __restrict__ b21,
    const float* __restrict__ w31, const float* __restrict__ b31,
    const float* __restrict__ w12, const float* __restrict__ b12,
    const float* __restrict__ w22, const float* __restrict__ b22,
    const float* __restrict__ w32, const float* __restrict__ b32,
    const float* __restrict__ w13, const float* __restrict__ b13,
    const float* __restrict__ w23, const float* __restrict__ b23,
    const float* __restrict__ w33, const float* __restrict__ b33,
    float* __restrict__ mods)
{
    int blk = blockIdx.x;
    int b = blk >> 2, m = blk & 3;
    const float* W1 = m==0?w10 : m==1?w11 : m==2?w12 : w13;
    const float* B1 = m==0?b10 : m==1?b11 : m==2?b12 : b13;
    const float* W2 = m==0?w20 : m==1?w21 : m==2?w22 : w23;
    const float* B2 = m==0?b20 : m==1?b21 : m==2?b22 : b23;
    const float* W3 = m==0?w30 : m==1?w31 : m==2?w32 : w33;
    const float* B3 = m==0?b30 : m==1?b31 : m==2?b32 : b33;
    int dout256 = (m == 0 || m == 2);
    int slot = (m==0)?0 : (m==1)?2 : (m==2)?3 : 5;

    __shared__ float xs[128], h1[128], h2[128];
    int t = threadIdx.x;
    xs[t] = nodes[b*128 + t] + tv[b];
    __syncthreads();

    float acc = B1[t];
    for (int i = 0; i < 128; i++) acc += xs[i] * W1[i*128 + t];
    h1[t] = silu_f(acc);
    __syncthreads();

    acc = B2[t];
    for (int i = 0; i < 128; i++) acc += h1[i] * W2[i*128 + t];
    h2[t] = silu_f(acc);
    __syncthreads();

    if (dout256) {
        float a0 = B3[t], a1 = B3[t + 128];
        for (int i = 0; i < 128; i++) {
            float h = h2[i];
            a0 += h * W3[i*256 + t];
            a1 += h * W3[i*256 + t + 128];
        }
        mods[((size_t)b*6 + slot    )*128 + t] = a0;
        mods[((size_t)b*6 + slot + 1)*128 + t] = a1;
    } else {
        float a0 = B3[t];
        for (int i = 0; i < 128; i++) a0 += h2[i] * W3[i*128 + t];
        mods[((size_t)b*6 + slot)*128 + t] = a0;
    }
}

// ---------------- K2: staticLN(ddof=1) + modulate + MFMA QKV -> bf16 ----------------
// grid = NB*8 blocks (b, 64-row tile), 256 threads (4 waves; wave = m-tile)
__global__ void __launch_bounds__(256, 1) k_norm_qkv(
    const float* __restrict__ latent, const float* __restrict__ mods,
    const float* __restrict__ qw, const float* __restrict__ kw, const float* __restrict__ vw,
    const float* __restrict__ qb, const float* __restrict__ kb, const float* __restrict__ vb,
    unsigned short* __restrict__ Qb, unsigned short* __restrict__ Kb,
    unsigned short* __restrict__ Vtb)
{
    __shared__ float xs[64*129];            // raw latent tile [n][d]
    __shared__ unsigned short xb[64*136];   // normalized bf16 [n][d] (also reused as V-out staging [128][68])
    __shared__ unsigned short WtS[128*136]; // W^T bf16 [c][d]
    __shared__ float g1s[128], be1s[128], mean_s[64], rstd_s[64];

    int blk = blockIdx.x;
    int b = blk >> 3, n0 = (blk & 7) * 64;
    int t = threadIdx.x;

    if (t < 128) {
        g1s[t]  = mods[((size_t)b*6 + 1)*128 + t];  // gamma1 = be1 (bug)
        be1s[t] = mods[((size_t)b*6 + 2)*128 + t];  // beta1  = al1 (bug)
    }
    const float* lp = latent + (size_t)b*65536 + n0;
    for (int idx = t; idx < 8192; idx += 256) {
        int d = idx >> 6, j = idx & 63;
        xs[j*129 + d] = lp[(size_t)d*512 + j];
    }
    __syncthreads();

    // LN stats: 4 lanes per row
    {
        int row = t >> 2, sub = t & 3;
        float s = 0.f, ss = 0.f;
        const float* xr = &xs[row*129 + sub*32];
        #pragma unroll
        for (int i = 0; i < 32; i++) { float v = xr[i]; s += v; ss += v*v; }
        s += __shfl_xor(s, 1); ss += __shfl_xor(ss, 1);
        s += __shfl_xor(s, 2); ss += __shfl_xor(ss, 2);
        float mean = s * (1.0f/128.0f);
        float var = (ss - 128.0f*mean*mean) * (1.0f/127.0f);
        var = var < 0.f ? 0.f : var;
        float sd = sqrtf(var);
        mean_s[row] = mean;
        rstd_s[row] = (sd == 0.f) ? 1.f : 1.f/sd;
    }
    __syncthreads();

    for (int idx = t; idx < 8192; idx += 256) {
        int j = idx >> 7, d = idx & 127;
        float v = xs[j*129 + d];
        xb[j*136 + d] = f2bf(g1s[d]*((v - mean_s[j]) * rstd_s[j]) + be1s[d]);
    }
    __syncthreads();

    int w = t >> 6, lane = t & 63, lo = lane & 15, hi = lane >> 4;

    // preload a-frags (this wave's 16 rows, all K=128)
    bf16x8 af[4];
    #pragma unroll
    for (int kc = 0; kc < 4; kc++)
        af[kc] = *(const bf16x8*)(xb + (w*16 + lo)*136 + kc*32 + hi*8);

    const f32x4 zero = {0.f, 0.f, 0.f, 0.f};
    const float qscale = 0.17677669529663687f;

    #pragma unroll 1
    for (int ph = 0; ph < 3; ph++) {
        const float* wp = ph==0 ? qw : (ph==1 ? kw : vw);
        __syncthreads();   // all waves done reading WtS (and xb for af) before restage
        for (int idx = t; idx < 16384; idx += 256) {
            int kk = idx & 31, d = (idx >> 5) & 127, h = idx >> 12;
            WtS[(h*32 + kk)*136 + d] = f2bf(wp[idx]);
        }
        __syncthreads();

        for (int nt = 0; nt < 8; nt++) {
            f32x4 acc = zero;
            #pragma unroll
            for (int kc = 0; kc < 4; kc++) {
                bf16x8 bf = *(const bf16x8*)(WtS + (nt*16 + lo)*136 + kc*32 + hi*8);
                acc = __builtin_amdgcn_mfma_f32_16x16x32_bf16(af[kc], bf, acc, 0, 0, 0);
            }
            int c = nt*16 + lo, h = c >> 5, kk = c & 31;
            size_t bh = (size_t)(b*4 + h);
            if (ph == 0) {
                float bias = qb[c];
                #pragma unroll
                for (int j = 0; j < 4; j++) {
                    int n = n0 + w*16 + hi*4 + j;
                    Qb[(bh*512 + n)*32 + kk] = f2bf((acc[j] + bias) * qscale);
                }
            } else if (ph == 1) {
                float bias = kb[c];
                #pragma unroll
                for (int j = 0; j < 4; j++) {
                    int n = n0 + w*16 + hi*4 + j;
                    Kb[(bh*512 + n)*32 + kk] = f2bf(acc[j] + bias);
                }
            } else {
                // stage V into LDS transposed [c][n-local], then coalesced write-out
                float bias = vb[c];
                #pragma unroll
                for (int j = 0; j < 4; j++) {
                    int nl = w*16 + hi*4 + j;
                    xb[c*68 + nl] = f2bf(acc[j] + bias);
                }
            }
        }
    }
    __syncthreads();
    // V write-out: Vtb[bh][kk][n0..n0+63] <- xb[c][0..63], coalesced 64-wide
    for (int idx = t; idx < 8192; idx += 256) {
        int c = idx >> 6, j = idx & 63;
        int h = c >> 5, kk = c & 31;
        size_t bh = (size_t)(b*4 + h);
        Vtb[(bh*32 + kk)*512 + n0 + j] = xb[c*68 + j];
    }
}

// ---------------- K3: MFMA attention per (b,h) ----------------
// grid = NB*4 blocks, 256 threads (4 waves). Each wave: 128 q-rows.
__global__ void __launch_bounds__(256, 1) k_attn(
    const unsigned short* __restrict__ Qb, const unsigned short* __restrict__ Kb,
    const unsigned short* __restrict__ Vtb, unsigned short* __restrict__ Ob)
{
    __shared__ unsigned short KsS[512*32];
    __shared__ unsigned short VsS[32*512];
    __shared__ unsigned short Ps[4][16*512];

    int bh = blockIdx.x;
    int t = threadIdx.x;

    const unsigned short* kgp = Kb + (size_t)bh*512*32;
    const unsigned short* vgp = Vtb + (size_t)bh*32*512;
    for (int idx = t; idx < 2048; idx += 256) {
        *(bf16x8*)(KsS + idx*8) = *(const bf16x8*)(kgp + idx*8);
    }
    for (int idx = t; idx < 2048; idx += 256) {
        int r = idx >> 6, cch = idx & 63;
        *(bf16x8*)(VsS + r*512 + ((cch*8) ^ ((r&7)<<3))) =
            *(const bf16x8*)(vgp + r*512 + cch*8);
    }
    __syncthreads();

    int w = t >> 6, lane = t & 63, lo = lane & 15, hi = lane >> 4;
    unsigned short* Pw = &Ps[w][0];
    const unsigned short* qbase = Qb + (size_t)bh*512*32;

    const f32x4 zero = {0.f, 0.f, 0.f, 0.f};
    int b = bh >> 2, h = bh & 3;

    for (int qt = 0; qt < 8; ++qt) {
        int q0 = w*128 + qt*16;
        bf16x8 qa = *(const bf16x8*)(qbase + (size_t)(q0 + lo)*32 + hi*8);

        f32x4 s[32];
        #pragma unroll
        for (int kt = 0; kt < 32; ++kt) {
            bf16x8 kf = *(const bf16x8*)(KsS + (kt*16 + lo)*32 + hi*8);
            s[kt] = __builtin_amdgcn_mfma_f32_16x16x32_bf16(qa, kf, zero, 0, 0, 0);
        }

        float mrow[4] = {-1e30f, -1e30f, -1e30f, -1e30f};
        #pragma unroll
        for (int kt = 0; kt < 32; ++kt) {
            #pragma unroll
            for (int j = 0; j < 4; ++j) mrow[j] = fmaxf(mrow[j], s[kt][j]);
        }
        #pragma unroll
        for (int j = 0; j < 4; ++j) {
            #pragma unroll
            for (int off = 1; off < 16; off <<= 1)
                mrow[j] = fmaxf(mrow[j], __shfl_xor(mrow[j], off));
        }

        float ssum[4] = {0.f, 0.f, 0.f, 0.f};
        #pragma unroll
        for (int kt = 0; kt < 32; ++kt) {
            #pragma unroll
            for (int j = 0; j < 4; ++j) {
                float p = __expf(s[kt][j] - mrow[j]);
                ssum[j] += p;
                int row = hi*4 + j;
                Pw[row*512 + ((kt*16 + lo) ^ ((row&7)<<3))] = f2bf(p);
            }
        }
        #pragma unroll
        for (int j = 0; j < 4; ++j) {
            #pragma unroll
            for (int off = 1; off < 16; off <<= 1)
                ssum[j] += __shfl_xor(ssum[j], off);
        }

        f32x4 oa = zero, ob = zero;
        const unsigned short* Pl = Pw + lo*512;
        const unsigned short* Vl0 = VsS + lo*512;
        const unsigned short* Vl1 = VsS + (16 + lo)*512;
        int swz = (lo & 7) << 3;
        #pragma unroll
        for (int cc = 0; cc < 16; ++cc) {
            int off = (cc*32 + hi*8) ^ swz;
            bf16x8 pa = *(const bf16x8*)(Pl + off);
            bf16x8 v0 = *(const bf16x8*)(Vl0 + off);
            bf16x8 v1 = *(const bf16x8*)(Vl1 + off);
            oa = __builtin_amdgcn_mfma_f32_16x16x32_bf16(pa, v0, oa, 0, 0, 0);
            ob = __builtin_amdgcn_mfma_f32_16x16x32_bf16(pa, v1, ob, 0, 0, 0);
        }

        // store bf16 O in permuted i-order: i = k*4 + h  (k = lo / lo+16)
        unsigned short* op = Ob + ((size_t)(b*512 + q0 + hi*4))*128 + h;
        #pragma unroll
        for (int j = 0; j < 4; ++j) {
            float invj = 1.f / ssum[j];
            op[(size_t)j*128 + lo*4]        = f2bf(oa[j] * invj);
            op[(size_t)j*128 + (lo+16)*4]   = f2bf(ob[j] * invj);
        }
    }
}

// ---------------- K4: MFMA O@ow + residual + staticLN2 + residual + transpose-out ----
// grid = NB*8 blocks, 256 threads (4 waves; wave = m-tile)
__global__ void __launch_bounds__(256, 2) k_out(
    const float* __restrict__ latent, const unsigned short* __restrict__ Ob,
    const float* __restrict__ ow, const float* __restrict__ mods,
    float* __restrict__ outp)
{
    __shared__ unsigned short owT[128*136];  // ow^T bf16 [c][i]
    __shared__ float xs[64*129];
    __shared__ float a1s[128], a2s[128], g2s[128], b2s[128];
    __shared__ float mean_s[64], rstd_s[64];

    int blk = blockIdx.x;
    int b = blk >> 3, n0 = (blk & 7) * 64;
    int t = threadIdx.x;

    if (t < 128) {
        a1s[t] = mods[((size_t)b*6 + 0)*128 + t];  // alpha1 = g1 (bug)
        a2s[t] = mods[((size_t)b*6 + 3)*128 + t];  // alpha2 = g2 (bug)
        g2s[t] = mods[((size_t)b*6 + 4)*128 + t];  // gamma2 = be2 (bug)
        b2s[t] = mods[((size_t)b*6 + 5)*128 + t];  // beta2  = al2 (bug)
    }
    for (int idx = t; idx < 16384; idx += 256) {
        int i = idx >> 7, c = idx & 127;
        owT[c*136 + i] = f2bf(ow[idx]);
    }
    const float* lp = latent + (size_t)b*65536 + n0;
    for (int idx = t; idx < 8192; idx += 256) {
        int d = idx >> 6, j = idx & 63;
        xs[j*129 + d] = lp[(size_t)d*512 + j];
    }
    __syncthreads();

    int w = t >> 6, lane = t & 63, lo = lane & 15, hi = lane >> 4;

    // a-frags from global Ob (L2-resident), rows b*512+n0+w*16+lo
    const unsigned short* arow = Ob + ((size_t)(b*512 + n0 + w*16 + lo))*128;
    bf16x8 af[4];
    #pragma unroll
    for (int kc = 0; kc < 4; kc++)
        af[kc] = *(const bf16x8*)(arow + kc*32 + hi*8);

    const f32x4 zero = {0.f, 0.f, 0.f, 0.f};
    for (int nt = 0; nt < 8; nt++) {
        f32x4 acc = zero;
        #pragma unroll
        for (int kc = 0; kc < 4; kc++) {
            bf16x8 bf = *(const bf16x8*)(owT + (nt*16 + lo)*136 + kc*32 + hi*8);
            acc = __builtin_amdgcn_mfma_f32_16x16x32_bf16(af[kc], bf, acc, 0, 0, 0);
        }
        int c = nt*16 + lo;
        #pragma unroll
        for (int j = 0; j < 4; j++) {
            int nl = w*16 + hi*4 + j;
            xs[nl*129 + c] += a1s[c] * acc[j];   // conflict-free: bank = (4hi+16nt+lo)%32
        }
    }
    __syncthreads();

    // LN2 stats: 4 lanes per row
    {
        int row = t >> 2, sub = t & 3;
        float s = 0.f, ss = 0.f;
        const float* xr = &xs[row*129 + sub*32];
        #pragma unroll
        for (int i = 0; i < 32; i++) { float v = xr[i]; s += v; ss += v*v; }
        s += __shfl_xor(s, 1); ss += __shfl_xor(ss, 1);
        s += __shfl_xor(s, 2); ss += __shfl_xor(ss, 2);
        float mean = s * (1.0f/128.0f);
        float var = (ss - 128.0f*mean*mean) * (1.0f/127.0f);
        var = var < 0.f ? 0.f : var;
        float sd = sqrtf(var);
        mean_s[row] = mean;
        rstd_s[row] = (sd == 0.f) ? 1.f : 1.f/sd;
    }
    __syncthreads();

    float* outb = outp + (size_t)b*65536 + n0;
    for (int idx = t; idx < 8192; idx += 256) {
        int d = idx >> 6, j = idx & 63;
        float v = xs[j*129 + d];
        float nv = (v - mean_s[j]) * rstd_s[j];
        outb[(size_t)d*512 + j] = v + a2s[d]*(g2s[d]*nv + b2s[d]);
    }
}

extern "C" void kernel_launch(void* const* d_in, const int* in_sizes, int n_in,
                              void* d_out, int out_size, void* d_ws, size_t ws_size,
                              hipStream_t stream) {
    const float* latent = (const float*)d_in[0];
    const float* nodes  = (const float*)d_in[1];
    const float* tv     = (const float*)d_in[2];
    const float* qw     = (const float*)d_in[3];
    const float* kw     = (const float*)d_in[4];
    const float* vw     = (const float*)d_in[5];
    const float* qb     = (const float*)d_in[6];
    const float* kb     = (const float*)d_in[7];
    const float* vb     = (const float*)d_in[8];
    const float* owp    = (const float*)d_in[9];

    const float* mw[24];
    for (int i = 0; i < 24; i++) mw[i] = (const float*)d_in[10 + i];

    char* wsb = (char*)d_ws;
    unsigned short* Qb  = (unsigned short*)(wsb);
    unsigned short* Kb  = (unsigned short*)(wsb + 8388608);
    unsigned short* Vtb = (unsigned short*)(wsb + 16777216);
    unsigned short* Ob  = (unsigned short*)(wsb + 25165824);
    float* mods = (float*)(wsb + 33554432);

    float* outp = (float*)d_out;

    k_cond<<<dim3(NB*4), dim3(128), 0, stream>>>(
        nodes, tv,
        mw[0], mw[1], mw[2], mw[3], mw[4], mw[5],
        mw[6], mw[7], mw[8], mw[9], mw[10], mw[11],
        mw[12], mw[13], mw[14], mw[15], mw[16], mw[17],
        mw[18], mw[19], mw[20], mw[21], mw[22], mw[23],
        mods);

    k_norm_qkv<<<dim3(NB*8), dim3(256), 0, stream>>>(
        latent, mods, qw, kw, vw, qb, kb, vb, Qb, Kb, Vtb);

    k_attn<<<dim3(NB*4), dim3(256), 0, stream>>>(Qb, Kb, Vtb, Ob);

    k_out<<<dim3(NB*8), dim3(256), 0, stream>>>(latent, Ob, owp, mods, outp);
}